// Round 1
// baseline (6234.808 us; speedup 1.0000x reference)
//
#include <hip/hip_runtime.h>
#include <math.h>

#define STEPS 2048
#define BATCH 512
#define S 8
#define HID 128
#define HEADS 89      // 9 (W_in) + 80 (W_out) output rows
#define HSTRIDE 132   // 128 + 4 pad, keeps float4 alignment, spreads banks

// ---------------------------------------------------------------------------
// Kernel 1: baseflow[b] = 25th percentile (linear interp) of flow[:, b]
// flow[t,b] = hyd[(t*BATCH+b)*17 + 0]
// ---------------------------------------------------------------------------
__global__ __launch_bounds__(256) void baseflow_kernel(
    const float* __restrict__ hyd, float* __restrict__ bf)
{
    __shared__ float arr[STEPS];
    const int b = blockIdx.x;
    const int tid = threadIdx.x;
    for (int t = tid; t < STEPS; t += 256)
        arr[t] = hyd[(size_t)(t * BATCH + b) * 17];
    __syncthreads();
    // bitonic sort ascending
    for (int k = 2; k <= STEPS; k <<= 1) {
        for (int j = k >> 1; j > 0; j >>= 1) {
            for (int i = tid; i < STEPS; i += 256) {
                int ixj = i ^ j;
                if (ixj > i) {
                    float a = arr[i], c = arr[ixj];
                    bool up = ((i & k) == 0);
                    if (up ? (a > c) : (a < c)) { arr[i] = c; arr[ixj] = a; }
                }
            }
            __syncthreads();
        }
    }
    if (tid == 0) {
        // position = 0.25*(2048-1) = 511.75
        bf[b] = arr[511] + 0.75f * (arr[512] - arr[511]);
    }
}

// ---------------------------------------------------------------------------
// Kernel 2: the 2048-step recurrence. One block = 2 batch columns.
// Thread t: hidden unit i = t&127 for batch slot g = t>>7.
// W0/W1 rows live in registers; head weights in LDS.
// ---------------------------------------------------------------------------
__global__ __launch_bounds__(256, 1) void hyd_step_kernel(
    const float* __restrict__ hyd,
    const float* __restrict__ W0,  const float* __restrict__ b0,
    const float* __restrict__ W1,  const float* __restrict__ b1,
    const float* __restrict__ Win, const float* __restrict__ bin,
    const float* __restrict__ Wout,const float* __restrict__ bout,
    const float* __restrict__ baseflow,
    float* __restrict__ out)
{
    __shared__ float Whs[HEADS * HSTRIDE];   // 46.9 KB
    __shared__ float h1s[2 * HID];
    __shared__ float h2s[2 * HID];
    __shared__ float xbuf[2 * 16];
    __shared__ float lg[2 * 16];             // 9 logits per batch slot
    __shared__ float bsig[2 * 80];           // sigmoid(b) per batch slot
    __shared__ float storesS[2 * S];
    __shared__ float bfS[2];

    const int tid = threadIdx.x;
    const int blk = blockIdx.x;          // 0..255
    const int i   = tid & 127;           // hidden unit
    const int gw  = tid >> 7;            // batch slot for L0/L1 phases

    // --- one-time register preload: W0 row, W1 row, biases ---
    float w0r[24];
    #pragma unroll
    for (int k = 0; k < 24; ++k) w0r[k] = W0[i * 24 + k];
    const float b0r = b0[i];
    const float b1r = b1[i];
    float4 w1r[32];
    const float4* w1row = (const float4*)(W1 + i * 128);
    #pragma unroll
    for (int j = 0; j < 32; ++j) w1r[j] = w1row[j];

    // --- stage head weights into LDS (rows 0..8 = W_in, 9..88 = W_out) ---
    for (int idx = tid; idx < HEADS * 128; idx += 256) {
        int r = idx >> 7, c = idx & 127;
        float v = (r < 9) ? Win[r * 128 + c] : Wout[(r - 9) * 128 + c];
        Whs[r * HSTRIDE + c] = v;
    }
    // head task mapping: tid<178 -> row ho = tid>>1, batch slot hg = tid&1
    const int ho = tid >> 1;
    const int hg = tid & 1;
    float hbr = 0.0f;
    if (tid < 2 * HEADS) hbr = (ho < 9) ? bin[ho] : bout[ho - 9];

    if (tid < 16) {
        int g = tid >> 3, j = tid & 7;
        storesS[g * S + j] = (j == 1) ? 1.0f : 0.0f;
    }
    if (tid < 2) bfS[tid] = baseflow[blk * 2 + tid];
    __syncthreads();

    for (int t = 0; t < STEPS; ++t) {
        // load x_t (16 inputs) for both batch columns
        if (tid < 32) {
            int g = tid >> 4, k = tid & 15;
            int batch = blk * 2 + g;
            xbuf[g * 16 + k] = hyd[((size_t)t * BATCH + batch) * 17 + 1 + k];
        }
        __syncthreads();   // B1: xbuf + storesS(prev step) ready

        // --- L0: h1 = relu(W0 @ [x, 0.01*stores] + b0) ---
        {
            float acc = b0r;
            #pragma unroll
            for (int k = 0; k < 16; ++k) acc += w0r[k] * xbuf[gw * 16 + k];
            #pragma unroll
            for (int k = 0; k < 8; ++k)  acc += w0r[16 + k] * (0.01f * storesS[gw * S + k]);
            h1s[gw * HID + i] = fmaxf(acc, 0.0f);
        }
        __syncthreads();   // B2

        // --- L1: h2 = relu(W1 @ h1 + b1) ---
        {
            const float4* hv = (const float4*)(h1s + gw * HID);
            float ax = 0.f, ay = 0.f, az = 0.f, aw = 0.f;
            #pragma unroll
            for (int j = 0; j < 32; ++j) {
                float4 h4 = hv[j];
                ax += w1r[j].x * h4.x;
                ay += w1r[j].y * h4.y;
                az += w1r[j].z * h4.z;
                aw += w1r[j].w * h4.w;
            }
            float acc = b1r + ((ax + ay) + (az + aw));
            h2s[gw * HID + i] = fmaxf(acc, 0.0f);
        }
        __syncthreads();   // B3

        // --- heads: logits (9) and sigmoid gates (80) ---
        if (tid < 2 * HEADS) {
            const float4* wrow = (const float4*)(Whs + ho * HSTRIDE);
            const float4* hv   = (const float4*)(h2s + hg * HID);
            float ax = 0.f, ay = 0.f, az = 0.f, aw = 0.f;
            #pragma unroll
            for (int j = 0; j < 32; ++j) {
                float4 w4 = wrow[j];
                float4 h4 = hv[j];
                ax += w4.x * h4.x;
                ay += w4.y * h4.y;
                az += w4.z * h4.z;
                aw += w4.w * h4.w;
            }
            float acc = hbr + ((ax + ay) + (az + aw));
            if (ho < 9) lg[hg * 16 + ho] = acc;
            else        bsig[hg * 80 + (ho - 9)] = 1.0f / (1.0f + __expf(-acc));
        }
        __syncthreads();   // B4

        // --- store update: 16 lanes of wave 0 (g = lane>>3, j = lane&7) ---
        if (tid < 16) {
            const int g = tid >> 3, j = tid & 7;
            // softmax over 9 logits, take a[j+1]
            float m = lg[g * 16 + 0];
            #pragma unroll
            for (int o = 1; o < 9; ++o) m = fmaxf(m, lg[g * 16 + o]);
            float den = 0.f;
            #pragma unroll
            for (int o = 0; o < 9; ++o) den += __expf(lg[g * 16 + o] - m);
            float aj = __expf(lg[g * 16 + (j + 1)] - m) / den;

            float rain = xbuf[g * 16 + 0];
            float s = storesS[g * S + j] + aj * rain;

            // redistribution loop (serial over d)
            #pragma unroll
            for (int d = 0; d < 8; ++d) {
                float fb = bsig[g * 80 + d * 8 + j] * s;
                float fsum = fb;
                fsum += __shfl_xor(fsum, 1);
                fsum += __shfl_xor(fsum, 2);
                fsum += __shfl_xor(fsum, 4);
                s -= fb;
                if (j == d) s += fsum;
            }
            // escape
            s -= bsig[g * 80 + 64 + j] * s;
            // flow
            float bflow = bsig[g * 80 + 72 + j];
            float fd = bflow * s;
            s -= fd;
            float fsum = fd;
            fsum += __shfl_xor(fsum, 1);
            fsum += __shfl_xor(fsum, 2);
            fsum += __shfl_xor(fsum, 4);
            // t==0 baseflow correction (after everything, replaces stores[2])
            if (t == 0 && j == 2) s = bfS[g] / fmaxf(bflow, 1e-5f);

            storesS[g * S + j] = s;
            if (j == 0) out[(size_t)t * BATCH + blk * 2 + g] = fsum;
        }
        // next iteration's B1 orders storesS write before L0 read
    }
}

// ---------------------------------------------------------------------------
extern "C" void kernel_launch(void* const* d_in, const int* in_sizes, int n_in,
                              void* d_out, int out_size, void* d_ws, size_t ws_size,
                              hipStream_t stream)
{
    const float* hyd  = (const float*)d_in[0];
    const float* W0   = (const float*)d_in[1];
    const float* b0   = (const float*)d_in[2];
    const float* W1   = (const float*)d_in[3];
    const float* b1   = (const float*)d_in[4];
    const float* Win  = (const float*)d_in[5];
    const float* bin  = (const float*)d_in[6];
    const float* Wout = (const float*)d_in[7];
    const float* bout = (const float*)d_in[8];
    float* out = (float*)d_out;
    float* bf  = (float*)d_ws;   // 512 floats of scratch

    baseflow_kernel<<<BATCH, 256, 0, stream>>>(hyd, bf);
    hyd_step_kernel<<<BATCH / 2, 256, 0, stream>>>(
        hyd, W0, b0, W1, b1, Win, bin, Wout, bout, bf, out);
}

// Round 2
// 4514.349 us; speedup vs baseline: 1.3811x; 1.3811x over previous
//
#include <hip/hip_runtime.h>
#include <math.h>

#define STEPS 2048
#define BATCH 512
#define NCOL 2   // batch columns per block

typedef __attribute__((ext_vector_type(8))) short short8;
typedef __attribute__((ext_vector_type(4))) short short4v;
typedef __attribute__((ext_vector_type(4))) float f32x4;

__device__ __forceinline__ short f2bf(float f) {
    union { float f; unsigned u; } v; v.f = f;
    unsigned u = v.u;
    return (short)((u + 0x7FFFu + ((u >> 16) & 1u)) >> 16);  // RNE
}

// ---------------------------------------------------------------------------
// baseflow[b] = 25th percentile (linear interp) of flow[:, b]
// ---------------------------------------------------------------------------
__global__ __launch_bounds__(256) void baseflow_kernel(
    const float* __restrict__ hyd, float* __restrict__ bf)
{
    __shared__ float arr[STEPS];
    const int b = blockIdx.x;
    const int tid = threadIdx.x;
    for (int t = tid; t < STEPS; t += 256)
        arr[t] = hyd[(size_t)(t * BATCH + b) * 17];
    __syncthreads();
    for (int k = 2; k <= STEPS; k <<= 1) {
        for (int j = k >> 1; j > 0; j >>= 1) {
            for (int i = tid; i < STEPS; i += 256) {
                int ixj = i ^ j;
                if (ixj > i) {
                    float a = arr[i], c = arr[ixj];
                    bool up = ((i & k) == 0);
                    if (up ? (a > c) : (a < c)) { arr[i] = c; arr[ixj] = a; }
                }
            }
            __syncthreads();
        }
    }
    if (tid == 0) bf[b] = arr[511] + 0.75f * (arr[512] - arr[511]);
}

// ---------------------------------------------------------------------------
// Recurrence: 256 blocks x 256 threads, 2 batch columns per block.
// MFMA 16x16x32 bf16 for L0/L1/heads; weights resident in register A-frags.
// LDS activation buffers are FRAGMENT-MAJOR: lane L's B-frag for K-tile kt
// sits at byte offset (kt*64 + L) * 16 -> ds_read_b128 fully linear,
// conflict-free.
//   B-layout assumed: B[k][n], n = lane&15, k = (lane>>4)*8 + j
//   C/D layout (verified): col = lane&15, row = (lane>>4)*4 + reg
// ---------------------------------------------------------------------------
__global__ __launch_bounds__(256, 1) void hyd_step_kernel(
    const float* __restrict__ hyd,
    const float* __restrict__ W0,  const float* __restrict__ b0,
    const float* __restrict__ W1,  const float* __restrict__ b1,
    const float* __restrict__ Win, const float* __restrict__ bin,
    const float* __restrict__ Wout,const float* __restrict__ bout,
    const float* __restrict__ baseflow,
    float* __restrict__ out)
{
    __shared__ __align__(16) short in0F[64 * 8];    // K=32 input frags
    __shared__ __align__(16) short h1F[256 * 8];    // K=128 h1 frags
    __shared__ __align__(16) short h2F[256 * 8];    // K=128 h2 frags
    __shared__ float lg[2 * 16];                    // 9 logits per column
    __shared__ float bsig[2 * 80];                  // sigmoid gates per column
    __shared__ float xraw[2][2];                    // rain, double-buffered

    const int tid  = threadIdx.x;
    const int blk  = blockIdx.x;
    const int lane = tid & 63;
    const int wv   = tid >> 6;
    const int cn   = lane & 15;   // column (n) of A/B/C frags
    const int cg   = lane >> 4;   // quad group

    // ---- zero LDS frag buffers (covers unused columns n>=2 forever) ----
    for (int i = tid; i < 64 * 8; i += 256) in0F[i] = 0;
    for (int i = tid; i < 256 * 8; i += 256) { h1F[i] = 0; h2F[i] = 0; }

    // ---- preload weight A-fragments + bias C-inits ----
    short8 a0[2]; f32x4 c0[2];
    short8 a1[2][4]; f32x4 c1[2];
    short8 ah[2][4]; f32x4 ch[2];
    #pragma unroll
    for (int i = 0; i < 2; ++i) {
        const int mt = 2 * wv + i;
        const int row = mt * 16 + cn;
        #pragma unroll
        for (int j = 0; j < 8; ++j) {
            int k = cg * 8 + j;
            a0[i][j] = (k < 24) ? f2bf(W0[row * 24 + k]) : (short)0;
        }
        #pragma unroll
        for (int kt = 0; kt < 4; ++kt)
            #pragma unroll
            for (int j = 0; j < 8; ++j)
                a1[i][kt][j] = f2bf(W1[row * 128 + kt * 32 + cg * 8 + j]);
        #pragma unroll
        for (int r = 0; r < 4; ++r) {
            int m = mt * 16 + cg * 4 + r;
            c0[i][r] = b0[m];
            c1[i][r] = b1[m];
        }
    }
    const int nht = (wv < 2) ? 2 : 1;
    int htile[2];
    htile[0] = (wv < 2) ? 2 * wv : 4 + (wv - 2);
    htile[1] = (wv < 2) ? 2 * wv + 1 : htile[0];
    #pragma unroll
    for (int i = 0; i < 2; ++i) {
        const int ht = htile[i];
        const int row = ht * 16 + cn;
        #pragma unroll
        for (int kt = 0; kt < 4; ++kt)
            #pragma unroll
            for (int j = 0; j < 8; ++j) {
                int k = kt * 32 + cg * 8 + j;
                float w = 0.f;
                if (row < 9)       w = Win[row * 128 + k];
                else if (row < 89) w = Wout[(row - 9) * 128 + k];
                ah[i][kt][j] = f2bf(w);
            }
        #pragma unroll
        for (int r = 0; r < 4; ++r) {
            int m = ht * 16 + cg * 4 + r;
            float bb = 0.f;
            if (m < 9)       bb = bin[m];
            else if (m < 89) bb = bout[m - 9];
            ch[i][r] = bb;
        }
    }

    // ---- recurrent store state: wave0 lane n (n<2) owns column n ----
    float sreg[8];
    #pragma unroll
    for (int j = 0; j < 8; ++j) sreg[j] = (j == 1) ? 1.f : 0.f;
    float bfv = 0.f;
    if (wv == 0 && lane < 2) bfv = baseflow[blk * NCOL + lane];

    // initial stores + x_0 into in0F
    if (wv == 0 && lane < 2) {
        short8 sp;
        #pragma unroll
        for (int j = 0; j < 8; ++j) sp[j] = f2bf(0.01f * sreg[j]);
        *(short8*)&in0F[(32 + lane) * 8] = sp;   // chunk (n, g=2) = k 16..23
    }
    if (wv == 1 && lane < 32) {
        int pn = lane >> 4, pk = lane & 15;
        float v = hyd[(size_t)(blk * NCOL + pn) * 17 + 1 + pk];
        in0F[((pk >> 3) * 16 + pn) * 8 + (pk & 7)] = f2bf(v);
        if (pk == 0) xraw[0][pn] = v;
    }
    __syncthreads();

    for (int t = 0; t < STEPS; ++t) {
        // prefetch x_{t+1} (wave 1)
        float xv = 0.f; int pn = 0, pk = 0;
        if (wv == 1 && lane < 32) {
            pn = lane >> 4; pk = lane & 15;
            int tn = (t + 1 < STEPS) ? (t + 1) : t;
            xv = hyd[((size_t)tn * BATCH + blk * NCOL + pn) * 17 + 1 + pk];
        }

        // === L0: h1 = relu(W0 @ [x, 0.01*stores] + b0) ===
        short8 bf0 = *(const short8*)&in0F[lane * 8];
        #pragma unroll
        for (int i = 0; i < 2; ++i) {
            f32x4 acc = __builtin_amdgcn_mfma_f32_16x16x32_bf16(a0[i], bf0, c0[i], 0, 0, 0);
            if (cn < NCOL) {
                int m0 = (2 * wv + i) * 16 + cg * 4;
                short4v p;
                #pragma unroll
                for (int r = 0; r < 4; ++r) p[r] = f2bf(fmaxf(acc[r], 0.f));
                *(short4v*)&h1F[((m0 >> 3) * 16 + cn) * 8 + (m0 & 7)] = p;
            }
        }
        __syncthreads();   // B1: h1F ready

        // write x_{t+1} into in0F (L0 read of step t is done)
        if (wv == 1 && lane < 32) {
            in0F[((pk >> 3) * 16 + pn) * 8 + (pk & 7)] = f2bf(xv);
            if (pk == 0) xraw[(t + 1) & 1][pn] = xv;
        }

        // === L1: h2 = relu(W1 @ h1 + b1) ===
        short8 bf1[4];
        #pragma unroll
        for (int kt = 0; kt < 4; ++kt)
            bf1[kt] = *(const short8*)&h1F[(kt * 64 + lane) * 8];
        #pragma unroll
        for (int i = 0; i < 2; ++i) {
            f32x4 acc = c1[i];
            #pragma unroll
            for (int kt = 0; kt < 4; ++kt)
                acc = __builtin_amdgcn_mfma_f32_16x16x32_bf16(a1[i][kt], bf1[kt], acc, 0, 0, 0);
            if (cn < NCOL) {
                int m0 = (2 * wv + i) * 16 + cg * 4;
                short4v p;
                #pragma unroll
                for (int r = 0; r < 4; ++r) p[r] = f2bf(fmaxf(acc[r], 0.f));
                *(short4v*)&h2F[((m0 >> 3) * 16 + cn) * 8 + (m0 & 7)] = p;
            }
        }
        __syncthreads();   // B2: h2F ready

        // === heads: 9 logits + 80 sigmoid gates ===
        short8 bf2[4];
        #pragma unroll
        for (int kt = 0; kt < 4; ++kt)
            bf2[kt] = *(const short8*)&h2F[(kt * 64 + lane) * 8];
        #pragma unroll
        for (int i = 0; i < 2; ++i) {
            if (i < nht) {
                f32x4 acc = ch[i];
                #pragma unroll
                for (int kt = 0; kt < 4; ++kt)
                    acc = __builtin_amdgcn_mfma_f32_16x16x32_bf16(ah[i][kt], bf2[kt], acc, 0, 0, 0);
                if (cn < NCOL) {
                    const int ht = htile[i];
                    #pragma unroll
                    for (int r = 0; r < 4; ++r) {
                        int m = ht * 16 + cg * 4 + r;
                        float v = acc[r];
                        if (m < 9)       lg[cn * 16 + m] = v;
                        else if (m < 89) bsig[cn * 80 + (m - 9)] = 1.f / (1.f + __expf(-v));
                    }
                }
            }
        }
        __syncthreads();   // B3: lg/bsig ready

        // === serial tail: wave0 lane n (n<2), all in registers ===
        if (wv == 0 && lane < 2) {
            const int n = lane;
            float mx = lg[n * 16 + 0];
            #pragma unroll
            for (int o = 1; o < 9; ++o) mx = fmaxf(mx, lg[n * 16 + o]);
            float den = __expf(lg[n * 16 + 0] - mx);
            float e[8];
            #pragma unroll
            for (int j = 0; j < 8; ++j) { e[j] = __expf(lg[n * 16 + j + 1] - mx); den += e[j]; }
            float rinv = xraw[t & 1][n] / den;   // rain / softmax denom
            #pragma unroll
            for (int j = 0; j < 8; ++j) sreg[j] += e[j] * rinv;

            #pragma unroll
            for (int d = 0; d < 8; ++d) {
                const float4* bp = (const float4*)&bsig[n * 80 + d * 8];
                float4 lo = bp[0], hi = bp[1];
                float fb[8];
                fb[0] = lo.x * sreg[0]; fb[1] = lo.y * sreg[1];
                fb[2] = lo.z * sreg[2]; fb[3] = lo.w * sreg[3];
                fb[4] = hi.x * sreg[4]; fb[5] = hi.y * sreg[5];
                fb[6] = hi.z * sreg[6]; fb[7] = hi.w * sreg[7];
                float fs = ((fb[0] + fb[1]) + (fb[2] + fb[3])) + ((fb[4] + fb[5]) + (fb[6] + fb[7]));
                #pragma unroll
                for (int j = 0; j < 8; ++j) sreg[j] -= fb[j];
                sreg[d] += fs;
            }
            {   // escape
                const float4* bp = (const float4*)&bsig[n * 80 + 64];
                float4 lo = bp[0], hi = bp[1];
                sreg[0] -= lo.x * sreg[0]; sreg[1] -= lo.y * sreg[1];
                sreg[2] -= lo.z * sreg[2]; sreg[3] -= lo.w * sreg[3];
                sreg[4] -= hi.x * sreg[4]; sreg[5] -= hi.y * sreg[5];
                sreg[6] -= hi.z * sreg[6]; sreg[7] -= hi.w * sreg[7];
            }
            float fsum;
            {   // flow
                const float4* bp = (const float4*)&bsig[n * 80 + 72];
                float4 lo = bp[0], hi = bp[1];
                float fd[8];
                fd[0] = lo.x * sreg[0]; fd[1] = lo.y * sreg[1];
                fd[2] = lo.z * sreg[2]; fd[3] = lo.w * sreg[3];
                fd[4] = hi.x * sreg[4]; fd[5] = hi.y * sreg[5];
                fd[6] = hi.z * sreg[6]; fd[7] = hi.w * sreg[7];
                #pragma unroll
                for (int j = 0; j < 8; ++j) sreg[j] -= fd[j];
                fsum = ((fd[0] + fd[1]) + (fd[2] + fd[3])) + ((fd[4] + fd[5]) + (fd[6] + fd[7]));
                if (t == 0) sreg[2] = bfv / fmaxf(lo.z, 1e-5f);  // b_flow[SLOW]
            }
            out[(size_t)t * BATCH + blk * NCOL + n] = fsum;
            short8 sp;
            #pragma unroll
            for (int j = 0; j < 8; ++j) sp[j] = f2bf(0.01f * sreg[j]);
            *(short8*)&in0F[(32 + n) * 8] = sp;
        }
        __syncthreads();   // B4: stores/in0F ready for next step
    }
}

// ---------------------------------------------------------------------------
extern "C" void kernel_launch(void* const* d_in, const int* in_sizes, int n_in,
                              void* d_out, int out_size, void* d_ws, size_t ws_size,
                              hipStream_t stream)
{
    const float* hyd  = (const float*)d_in[0];
    const float* W0   = (const float*)d_in[1];
    const float* b0   = (const float*)d_in[2];
    const float* W1   = (const float*)d_in[3];
    const float* b1   = (const float*)d_in[4];
    const float* Win  = (const float*)d_in[5];
    const float* bin  = (const float*)d_in[6];
    const float* Wout = (const float*)d_in[7];
    const float* bout = (const float*)d_in[8];
    float* out = (float*)d_out;
    float* bf  = (float*)d_ws;

    baseflow_kernel<<<BATCH, 256, 0, stream>>>(hyd, bf);
    hyd_step_kernel<<<BATCH / NCOL, 256, 0, stream>>>(
        hyd, W0, b0, W1, b1, Win, bin, Wout, bout, bf, out);
}

// Round 4
// 3380.214 us; speedup vs baseline: 1.8445x; 1.3355x over previous
//
#include <hip/hip_runtime.h>
#include <hip/hip_bf16.h>
#include <math.h>

#define STEPS 2048
#define BATCH 512

typedef __attribute__((ext_vector_type(8))) short short8;
typedef __attribute__((ext_vector_type(4))) short short4v;
typedef __attribute__((ext_vector_type(2))) short short2v;
typedef __attribute__((ext_vector_type(4))) float f32x4;

__device__ __forceinline__ short f2bf(float f) {
    union { float f; unsigned u; } v; v.f = f;
    unsigned u = v.u;
    return (short)((u + 0x7FFFu + ((u >> 16) & 1u)) >> 16);  // RNE
}
__device__ __forceinline__ short2v pk2(float a, float b) {
    __hip_bfloat162 h = __float22bfloat162_rn(make_float2(a, b));
    union { __hip_bfloat162 h; short2v s; } u; u.h = h; return u.s;
}

// ---------------------------------------------------------------------------
// baseflow[b] = 25th percentile (linear interp) of flow[:, b]
// ---------------------------------------------------------------------------
__global__ __launch_bounds__(256) void baseflow_kernel(
    const float* __restrict__ hyd, float* __restrict__ bf)
{
    __shared__ float arr[STEPS];
    const int b = blockIdx.x;
    const int tid = threadIdx.x;
    for (int t = tid; t < STEPS; t += 256)
        arr[t] = hyd[(size_t)(t * BATCH + b) * 17];
    __syncthreads();
    for (int k = 2; k <= STEPS; k <<= 1) {
        for (int j = k >> 1; j > 0; j >>= 1) {
            for (int i = tid; i < STEPS; i += 256) {
                int ixj = i ^ j;
                if (ixj > i) {
                    float a = arr[i], c = arr[ixj];
                    bool up = ((i & k) == 0);
                    if (up ? (a > c) : (a < c)) { arr[i] = c; arr[ixj] = a; }
                }
            }
            __syncthreads();
        }
    }
    if (tid == 0) bf[b] = arr[511] + 0.75f * (arr[512] - arr[511]);
}

// ---------------------------------------------------------------------------
// 256 blocks x 256 threads (4 waves), 2 batch columns per block.
//  - x_t pre-staged in LDS ring (16 steps/refill)
//  - stores recurrence in registers, tail redundant on all lanes (col=lane&1)
//  - head epilogue: exp(logit) (no max-sub; logits O(1)) + sigmoid(gate)
//  - 3 barriers/step
// NOTE: rain = hyd[...,1] (x[:,:,0]); hyd[...,0] is flow (R3 bug).
// ---------------------------------------------------------------------------
__global__ __launch_bounds__(256, 1) void hyd_step_kernel(
    const float* __restrict__ hyd,
    const float* __restrict__ W0,  const float* __restrict__ b0,
    const float* __restrict__ W1,  const float* __restrict__ b1,
    const float* __restrict__ Win, const float* __restrict__ bin,
    const float* __restrict__ Wout,const float* __restrict__ bout,
    const float* __restrict__ baseflow,
    float* __restrict__ out)
{
    __shared__ __align__(16) short h1F[256 * 8];
    __shared__ __align__(16) short h2F[256 * 8];
    __shared__ __align__(16) short ringX[16 * 4 * 8];  // [slot][g2*2+col][j]
    __shared__ float ringR[16][2];                     // rain (hyd[...,1]), fp32
    __shared__ __align__(16) float hb[2][96];          // m<9: exp(logit); else sigmoid

    const int tid  = threadIdx.x;
    const int blk  = blockIdx.x;
    const int lane = tid & 63;
    const int wv   = tid >> 6;
    const int cn   = lane & 15;
    const int cg   = lane >> 4;
    const int col  = lane & 1;    // tail column owned by this lane

    for (int i = tid; i < 256 * 8; i += 256) { h1F[i] = 0; h2F[i] = 0; }

    // ---- weight A-fragments + bias C-inits (one-time) ----
    short8 a0[2]; f32x4 c0[2];
    short8 a1[2][4]; f32x4 c1[2];
    short8 ah[2][4]; f32x4 ch[2];
    #pragma unroll
    for (int i = 0; i < 2; ++i) {
        const int mt = 2 * wv + i;
        const int row = mt * 16 + cn;
        #pragma unroll
        for (int j = 0; j < 8; ++j) {
            int k = cg * 8 + j;
            a0[i][j] = (k < 24) ? f2bf(W0[row * 24 + k]) : (short)0;
        }
        #pragma unroll
        for (int kt = 0; kt < 4; ++kt)
            #pragma unroll
            for (int j = 0; j < 8; ++j)
                a1[i][kt][j] = f2bf(W1[row * 128 + kt * 32 + cg * 8 + j]);
        #pragma unroll
        for (int r = 0; r < 4; ++r) {
            int m = mt * 16 + cg * 4 + r;
            c0[i][r] = b0[m];
            c1[i][r] = b1[m];
        }
    }
    const int nht = (wv < 2) ? 2 : 1;
    int htile[2];
    htile[0] = (wv < 2) ? 2 * wv : 4 + (wv - 2);
    htile[1] = (wv < 2) ? 2 * wv + 1 : htile[0];
    #pragma unroll
    for (int i = 0; i < 2; ++i) {
        const int ht = htile[i];
        const int row = ht * 16 + cn;
        #pragma unroll
        for (int kt = 0; kt < 4; ++kt)
            #pragma unroll
            for (int j = 0; j < 8; ++j) {
                int k = kt * 32 + cg * 8 + j;
                float w = 0.f;
                if (row < 9)       w = Win[row * 128 + k];
                else if (row < 89) w = Wout[(row - 9) * 128 + k];
                ah[i][kt][j] = f2bf(w);
            }
        #pragma unroll
        for (int r = 0; r < 4; ++r) {
            int m = ht * 16 + cg * 4 + r;
            float bb = 0.f;
            if (m < 9)       bb = bin[m];
            else if (m < 89) bb = bout[m - 9];
            ch[i][r] = bb;
        }
    }

    // ---- recurrent state, replicated per lane for column col ----
    float sreg[8];
    #pragma unroll
    for (int j = 0; j < 8; ++j) sreg[j] = (j == 1) ? 1.f : 0.f;
    const float bfv = baseflow[blk * 2 + col];
    short8 spack;
    #pragma unroll
    for (int jj = 0; jj < 4; ++jj) {
        short2v p = pk2(0.01f * sreg[2 * jj], 0.01f * sreg[2 * jj + 1]);
        spack[2 * jj] = p[0]; spack[2 * jj + 1] = p[1];
    }

    for (int tb = 0; tb < STEPS; tb += 16) {
        // ---- ring refill: 16 steps of x (bf16 frag layout) + rain (fp32) ----
        if (tid < 64) {
            const int tp = tid >> 2, c = (tid >> 1) & 1, g2 = tid & 1;
            const float* p = hyd + ((size_t)(tb + tp) * BATCH + blk * 2 + c) * 17 + 1 + g2 * 8;
            float v0 = p[0], v1 = p[1], v2 = p[2], v3 = p[3];
            float v4 = p[4], v5 = p[5], v6 = p[6], v7 = p[7];
            short8 w;
            short2v q0 = pk2(v0, v1), q1 = pk2(v2, v3), q2 = pk2(v4, v5), q3 = pk2(v6, v7);
            w[0] = q0[0]; w[1] = q0[1]; w[2] = q1[0]; w[3] = q1[1];
            w[4] = q2[0]; w[5] = q2[1]; w[6] = q3[0]; w[7] = q3[1];
            *(short8*)&ringX[(tp * 4 + g2 * 2 + c) * 8] = w;
        } else if (tid < 96) {
            const int l = tid - 64, tp = l >> 1, c = l & 1;
            // rain = x[:,:,0] = hyd[...,1]  (index 0 is flow!)
            ringR[tp][c] = hyd[((size_t)(tb + tp) * BATCH + blk * 2 + c) * 17 + 1];
        }
        __syncthreads();   // refill done (also orders initial zero-fill)

        for (int tt = 0; tt < 16; ++tt) {
            const int t = tb + tt;

            // rain for the tail — read BEFORE B1 so next group's refill can't race
            const float rain = ringR[tt][col];

            // === L0: h1 = relu(W0 @ [x, 0.01*stores] + b0) ===
            short8 bfrag = 0;
            if (cn < 2) {
                if (cg < 2)        bfrag = *(const short8*)&ringX[(tt * 4 + cg * 2 + cn) * 8];
                else if (cg == 2)  bfrag = spack;
            }
            #pragma unroll
            for (int i = 0; i < 2; ++i) {
                f32x4 acc = __builtin_amdgcn_mfma_f32_16x16x32_bf16(a0[i], bfrag, c0[i], 0, 0, 0);
                if (cn < 2) {
                    int m0 = (2 * wv + i) * 16 + cg * 4;
                    short4v p;
                    short2v pa = pk2(fmaxf(acc[0], 0.f), fmaxf(acc[1], 0.f));
                    short2v pb = pk2(fmaxf(acc[2], 0.f), fmaxf(acc[3], 0.f));
                    p[0] = pa[0]; p[1] = pa[1]; p[2] = pb[0]; p[3] = pb[1];
                    *(short4v*)&h1F[((m0 >> 3) * 16 + cn) * 8 + (m0 & 7)] = p;
                }
            }
            __syncthreads();   // B1

            // === L1: h2 = relu(W1 @ h1 + b1) ===
            short8 bf1[4];
            #pragma unroll
            for (int kt = 0; kt < 4; ++kt)
                bf1[kt] = *(const short8*)&h1F[(kt * 64 + lane) * 8];
            #pragma unroll
            for (int i = 0; i < 2; ++i) {
                f32x4 acc = c1[i];
                #pragma unroll
                for (int kt = 0; kt < 4; ++kt)
                    acc = __builtin_amdgcn_mfma_f32_16x16x32_bf16(a1[i][kt], bf1[kt], acc, 0, 0, 0);
                if (cn < 2) {
                    int m0 = (2 * wv + i) * 16 + cg * 4;
                    short4v p;
                    short2v pa = pk2(fmaxf(acc[0], 0.f), fmaxf(acc[1], 0.f));
                    short2v pb = pk2(fmaxf(acc[2], 0.f), fmaxf(acc[3], 0.f));
                    p[0] = pa[0]; p[1] = pa[1]; p[2] = pb[0]; p[3] = pb[1];
                    *(short4v*)&h2F[((m0 >> 3) * 16 + cn) * 8 + (m0 & 7)] = p;
                }
            }
            __syncthreads();   // B2

            // === heads: exp(logits) for m<9, sigmoid(gates) for m>=9 ===
            short8 bf2[4];
            #pragma unroll
            for (int kt = 0; kt < 4; ++kt)
                bf2[kt] = *(const short8*)&h2F[(kt * 64 + lane) * 8];
            #pragma unroll
            for (int i = 0; i < 2; ++i) {
                if (i < nht) {
                    f32x4 acc = ch[i];
                    #pragma unroll
                    for (int kt = 0; kt < 4; ++kt)
                        acc = __builtin_amdgcn_mfma_f32_16x16x32_bf16(ah[i][kt], bf2[kt], acc, 0, 0, 0);
                    if (cn < 2) {
                        const int ht = htile[i];
                        float4 o;
                        #pragma unroll
                        for (int r = 0; r < 4; ++r) {
                            int m = ht * 16 + cg * 4 + r;
                            float v = acc[r];
                            bool isl = (m < 9);
                            float em = __expf(isl ? v : -v);
                            float res = isl ? em : __builtin_amdgcn_rcpf(1.f + em);
                            ((float*)&o)[r] = res;
                        }
                        *(float4*)&hb[cn][ht * 16 + cg * 4] = o;
                    }
                }
            }
            __syncthreads();   // B3

            // === tail: redundant on every lane, all in registers ===
            {
                float gv[92];
                const float4* hp = (const float4*)&hb[col][0];
                #pragma unroll
                for (int c2 = 0; c2 < 23; ++c2)
                    ((float4*)gv)[c2] = hp[c2];

                float den = ((gv[0] + gv[1]) + (gv[2] + gv[3])) +
                            ((gv[4] + gv[5]) + (gv[6] + gv[7])) + gv[8];
                float rr = rain * __builtin_amdgcn_rcpf(den);
                #pragma unroll
                for (int j = 0; j < 8; ++j) sreg[j] += gv[1 + j] * rr;

                #pragma unroll
                for (int d = 0; d < 8; ++d) {
                    float fb[8];
                    #pragma unroll
                    for (int j = 0; j < 8; ++j) fb[j] = gv[9 + d * 8 + j] * sreg[j];
                    float fs = ((fb[0] + fb[1]) + (fb[2] + fb[3])) +
                               ((fb[4] + fb[5]) + (fb[6] + fb[7]));
                    #pragma unroll
                    for (int j = 0; j < 8; ++j) sreg[j] -= fb[j];
                    sreg[d] += fs;
                }
                #pragma unroll
                for (int j = 0; j < 8; ++j) sreg[j] -= gv[73 + j] * sreg[j];   // escape
                float fd[8];
                #pragma unroll
                for (int j = 0; j < 8; ++j) fd[j] = gv[81 + j] * sreg[j];      // flow
                float fsum = ((fd[0] + fd[1]) + (fd[2] + fd[3])) +
                             ((fd[4] + fd[5]) + (fd[6] + fd[7]));
                #pragma unroll
                for (int j = 0; j < 8; ++j) sreg[j] -= fd[j];
                if (t == 0) sreg[2] = bfv / fmaxf(gv[83], 1e-5f);   // b_flow[SLOW]

                #pragma unroll
                for (int jj = 0; jj < 4; ++jj) {
                    short2v p = pk2(0.01f * sreg[2 * jj], 0.01f * sreg[2 * jj + 1]);
                    spack[2 * jj] = p[0]; spack[2 * jj + 1] = p[1];
                }
                if (tid < 2) out[(size_t)t * BATCH + blk * 2 + tid] = fsum;
            }
            // no B4: stores live in registers; h1F(t+1) writes are ordered
            // after every wave's h1F(t) reads by B2(t)/B3(t)
        }
    }
}

// ---------------------------------------------------------------------------
extern "C" void kernel_launch(void* const* d_in, const int* in_sizes, int n_in,
                              void* d_out, int out_size, void* d_ws, size_t ws_size,
                              hipStream_t stream)
{
    const float* hyd  = (const float*)d_in[0];
    const float* W0   = (const float*)d_in[1];
    const float* b0   = (const float*)d_in[2];
    const float* W1   = (const float*)d_in[3];
    const float* b1   = (const float*)d_in[4];
    const float* Win  = (const float*)d_in[5];
    const float* bin  = (const float*)d_in[6];
    const float* Wout = (const float*)d_in[7];
    const float* bout = (const float*)d_in[8];
    float* out = (float*)d_out;
    float* bf  = (float*)d_ws;

    baseflow_kernel<<<BATCH, 256, 0, stream>>>(hyd, bf);
    hyd_step_kernel<<<BATCH / 2, 256, 0, stream>>>(
        hyd, W0, b0, W1, b1, Win, bin, Wout, bout, bf, out);
}